// Round 5
// baseline (304.253 us; speedup 1.0000x reference)
//
#include <hip/hip_runtime.h>
#include <math.h>

#define HW 65536
#define BN 16
#define QCH 16384              // float4 quads per channel-image (HW/4)
#define PART_FLOATS 4194304    // B*BN*HW floats per partial array

// ws layout (floats):
//   ws[0] : mask-loss sum,  ws[1] : skin-loss sum
//   per-b block of 9 at ws[2 + b*9]:
//     +0..2 : nocs msum,cnt,dsum  +3..5 : locmap  +6..8 : rotmap
//   per-(b,j) block of 7 at ws[38 + (b*16+j)*7]: S, Nloc0..2, Nrot0..2
//   float offset 512            : dslpart[b][j][HW] (16 MB)
//   float offset 512+PART_FLOATS: dsrpart[b][j][HW] (16 MB)

__device__ __forceinline__ float fsig(float x) {
    return __builtin_amdgcn_rcpf(1.0f + __expf(-x));
}
__device__ __forceinline__ float sq(float x) { return x * x; }

__device__ __forceinline__ float wred(float v) {
#pragma unroll
    for (int off = 32; off; off >>= 1) v += __shfl_xor(v, off, 64);
    return v;
}
__device__ __forceinline__ float4 fsig4(float4 v) {
    return make_float4(fsig(v.x), fsig(v.y), fsig(v.z), fsig(v.w));
}
__device__ __forceinline__ float dot4(float4 a, float4 b) {
    return a.x * b.x + a.y * b.y + a.z * b.z + a.w * b.w;
}
__device__ __forceinline__ float4 sq3(float4 a0, float4 a1, float4 a2,
                                      float4 b0, float4 b1, float4 b2) {
    return make_float4(
        sq(a0.x - b0.x) + sq(a1.x - b1.x) + sq(a2.x - b2.x),
        sq(a0.y - b0.y) + sq(a1.y - b1.y) + sq(a2.y - b2.y),
        sq(a0.z - b0.z) + sq(a1.z - b1.z) + sq(a2.z - b2.z),
        sq(a0.w - b0.w) + sq(a1.w - b1.w) + sq(a2.w - b2.w));
}

__device__ __forceinline__ float skin_ce(const float* x, int lab) {
    float mx = x[0];
#pragma unroll
    for (int k = 1; k < 18; ++k) mx = fmaxf(mx, x[k]);
    float se = 0.0f;
#pragma unroll
    for (int k = 0; k < 18; ++k) se += __expf(x[k] - mx);
    lab = lab < 0 ? 0 : (lab > 17 ? 17 : lab);
    float xl = x[0];
#pragma unroll
    for (int k = 1; k < 18; ++k) xl = (lab == k) ? x[k] : xl;
    return mx + __logf(se) - xl;
}

// ===== K1: per-(b,j) streams — long contiguous runs =======================
// grid (16 slabs, 4 b, 16 j); block 256. Slab = 4096 px. Per channel the
// block reads 16 KB contiguous (4 wave-loads x 4 KB runs).
__global__ __launch_bounds__(256) void k1_joint(const float* __restrict__ outp,
                                                const float* __restrict__ tarp,
                                                float* __restrict__ ws) {
    const int t = threadIdx.x;
    const int slab = blockIdx.x;
    const int b = blockIdx.y;
    const int j = blockIdx.z;
    const int lane = t & 63, wv = t >> 6;
    const float4* ob = (const float4*)(outp + (size_t)b * 134 * HW);
    const float4* tb = (const float4*)(tarp + (size_t)b * 101 * HW);
    float4* dslp = ((float4*)(ws + 512)) + (size_t)(b * BN + j) * QCH;
    float4* dsrp = ((float4*)(ws + 512 + PART_FLOATS)) + (size_t)(b * BN + j) * QCH;

    const int cl = (4 + 3 * j) * QCH, cr = (52 + 3 * j) * QCH;
    const int cs = (118 + j) * QCH, cm = 3 * QCH;

    float S = 0.0f, NL0 = 0.0f, NL1 = 0.0f, NL2 = 0.0f,
          NR0 = 0.0f, NR1 = 0.0f, NR2 = 0.0f;

#pragma unroll 1
    for (int k = 0; k < 4; ++k) {
        const int q = slab * 1024 + k * 256 + t;
        // 14-load batch, all independent (14 KB/wave in flight)
        const float4 m  = tb[cm + q];
        const float4 s  = ob[cs + q];
        const float4 o0 = ob[cl + q];
        const float4 o1 = ob[cl + QCH + q];
        const float4 o2 = ob[cl + 2 * QCH + q];
        const float4 t0 = tb[cl + q];
        const float4 t1 = tb[cl + QCH + q];
        const float4 t2 = tb[cl + 2 * QCH + q];
        const float4 p0 = ob[cr + q];
        const float4 p1 = ob[cr + QCH + q];
        const float4 p2 = ob[cr + 2 * QCH + q];
        const float4 u0 = tb[cr + q];
        const float4 u1 = tb[cr + QCH + q];
        const float4 u2 = tb[cr + 2 * QCH + q];

        float4 w = fsig4(s);
        w.x *= m.x; w.y *= m.y; w.z *= m.z; w.w *= m.w;      // sig(score)*m
        S += w.x + w.y + w.z + w.w;
        float4 wm = w;
        wm.x *= m.x; wm.y *= m.y; wm.z *= m.z; wm.w *= m.w;  // sig(score)*m^2

        const float4 so0 = fsig4(o0), so1 = fsig4(o1), so2 = fsig4(o2);
        const float4 st0 = fsig4(t0), st1 = fsig4(t1), st2 = fsig4(t2);
        const float4 sp0 = fsig4(p0), sp1 = fsig4(p1), sp2 = fsig4(p2);
        const float4 su0 = fsig4(u0), su1 = fsig4(u1), su2 = fsig4(u2);

        dslp[q] = sq3(so0, so1, so2, st0, st1, st2);   // per-pixel partials
        dsrp[q] = sq3(sp0, sp1, sp2, su0, su1, su2);

        NL0 += dot4(so0, wm); NL1 += dot4(so1, wm); NL2 += dot4(so2, wm);
        NR0 += dot4(sp0, wm); NR1 += dot4(sp1, wm); NR2 += dot4(sp2, wm);
    }

    float v[7] = {S, NL0, NL1, NL2, NR0, NR1, NR2};
#pragma unroll
    for (int off = 32; off; off >>= 1) {
#pragma unroll
        for (int i = 0; i < 7; ++i) v[i] += __shfl_xor(v[i], off, 64);
    }
    __shared__ float red[7][4];
    if (lane == 0) {
#pragma unroll
        for (int i = 0; i < 7; ++i) red[i][wv] = v[i];
    }
    __syncthreads();
    if (t < 7) {
        float s = red[t][0] + red[t][1] + red[t][2] + red[t][3];
        atomicAdd(&ws[38 + (b * BN + j) * 7 + t], s);
    }
}

// ===== K2: per-pixel losses + partial gather ==============================
// grid (64, 4); block 256; 1 float4-quad/thread.
__global__ __launch_bounds__(256) void k2_pix(const float* __restrict__ outp,
                                              const float* __restrict__ tarp,
                                              float* __restrict__ ws) {
    const int b = blockIdx.y;
    const int q = blockIdx.x * 256 + threadIdx.x;     // 0..16383
    const int lane = threadIdx.x & 63, wv = threadIdx.x >> 6;
    const float4* ob = (const float4*)(outp + (size_t)b * 134 * HW);
    const float4* tb = (const float4*)(tarp + (size_t)b * 101 * HW);
    const float4* dslp = ((const float4*)(ws + 512)) + (size_t)b * BN * QCH + q;
    const float4* dsrp = ((const float4*)(ws + 512 + PART_FLOATS)) + (size_t)b * BN * QCH + q;

    const float4 m  = tb[3 * QCH + q];
    const float4 ml = ob[3 * QCH + q];
    const float4 a0 = ob[q], a1 = ob[QCH + q], a2 = ob[2 * QCH + q];
    const float4 b0 = tb[q], b1 = tb[QCH + q], b2 = tb[2 * QCH + q];
    const float4 labf = tb[100 * QCH + q];

    float x0[18], x1[18], x2[18], x3[18];
#pragma unroll
    for (int k = 0; k < 18; ++k) {
        float4 xv = ob[(100 + k) * QCH + q];
        x0[k] = xv.x; x1[k] = xv.y; x2[k] = xv.z; x3[k] = xv.w;
    }

    float4 dsl = make_float4(0.f, 0.f, 0.f, 0.f);
    float4 dsr = make_float4(0.f, 0.f, 0.f, 0.f);
#pragma unroll 4
    for (int j = 0; j < BN; ++j) {                     // L3-resident gather
        float4 a = dslp[(size_t)j * QCH];
        float4 c = dsrp[(size_t)j * QCH];
        dsl.x += a.x; dsl.y += a.y; dsl.z += a.z; dsl.w += a.w;
        dsr.x += c.x; dsr.y += c.y; dsr.z += c.z; dsr.w += c.w;
    }

    float v[11];
#pragma unroll
    for (int i = 0; i < 11; ++i) v[i] = 0.0f;

#define DO_COMP(C, XC)                                                         \
    {                                                                          \
        const float mc = m.C, mlc = ml.C;                                      \
        v[0] += mc * fminf(mlc, 0.f) + (1.f - mc) * fminf(-mlc, 0.f)           \
                - __logf(1.f + __expf(-fabsf(mlc)));                           \
        v[1] += skin_ce(XC, (int)labf.C);                                      \
        const float dn = sqrtf(sq(a0.C - b0.C) + sq(a1.C - b1.C) +             \
                               sq(a2.C - b2.C));                               \
        const bool sel = mc > 0.7f;                                            \
        v[2] += sel ? dn : 0.f;                                                \
        v[3] += (sel && dn != 0.f) ? 1.f : 0.f;                                \
        v[4] += dn;                                                            \
        const float dnl = sqrtf(dsl.C);                                        \
        v[5] += sel ? dnl : 0.f;                                               \
        v[6] += (sel && dnl != 0.f) ? 1.f : 0.f;                               \
        v[7] += dnl;                                                           \
        const float dnr = sqrtf(dsr.C);                                        \
        v[8] += sel ? dnr : 0.f;                                               \
        v[9] += (sel && dnr != 0.f) ? 1.f : 0.f;                               \
        v[10] += dnr;                                                          \
    }
    DO_COMP(x, x0)
    DO_COMP(y, x1)
    DO_COMP(z, x2)
    DO_COMP(w, x3)
#undef DO_COMP

#pragma unroll
    for (int off = 32; off; off >>= 1) {
#pragma unroll
        for (int i = 0; i < 11; ++i) v[i] += __shfl_xor(v[i], off, 64);
    }
    __shared__ float red[11][4];
    if (lane == 0) {
#pragma unroll
        for (int i = 0; i < 11; ++i) red[i][wv] = v[i];
    }
    __syncthreads();
    if (threadIdx.x < 11) {
        float s = red[threadIdx.x][0] + red[threadIdx.x][1] +
                  red[threadIdx.x][2] + red[threadIdx.x][3];
        int g = (threadIdx.x < 2) ? threadIdx.x : (2 + b * 9 + (threadIdx.x - 2));
        atomicAdd(&ws[g], s);
    }
}

// ===== Fallback path (round-4 kernels) if ws too small ====================
__global__ __launch_bounds__(256) void mvpm_pix2(const float* __restrict__ outp,
                                                 const float* __restrict__ tarp,
                                                 float* __restrict__ ws) {
    const int b = blockIdx.y;
    const int t = blockIdx.x * 256 + threadIdx.x;
    const int C2 = HW / 2;
    const float2* ob = (const float2*)(outp + (size_t)b * 134 * HW) + t;
    const float2* tb = (const float2*)(tarp + (size_t)b * 101 * HW) + t;
    const int lane = threadIdx.x & 63;
    const int wv = threadIdx.x >> 6;

    const float2 m2 = tb[3 * C2];
    const float2 ml = ob[3 * C2];
    const float2 a0 = ob[0], a1 = ob[C2], a2 = ob[2 * C2];
    const float2 b0 = tb[0], b1 = tb[C2], b2 = tb[2 * C2];

    const float bce =
        (m2.x * fminf(ml.x, 0.0f) + (1.0f - m2.x) * fminf(-ml.x, 0.0f)
         - __logf(1.0f + __expf(-fabsf(ml.x)))) +
        (m2.y * fminf(ml.y, 0.0f) + (1.0f - m2.y) * fminf(-ml.y, 0.0f)
         - __logf(1.0f + __expf(-fabsf(ml.y))));

    const float dnx = sqrtf(sq(a0.x - b0.x) + sq(a1.x - b1.x) + sq(a2.x - b2.x));
    const float dny = sqrtf(sq(a0.y - b0.y) + sq(a1.y - b1.y) + sq(a2.y - b2.y));
    const bool sx = m2.x > 0.7f, sy = m2.y > 0.7f;

    float xx[18], xy[18];
#pragma unroll
    for (int k = 0; k < 18; ++k) {
        float2 xv = ob[(100 + k) * C2];
        xx[k] = xv.x; xy[k] = xv.y;
    }
    const float2 labf = tb[100 * C2];
    const float skin = skin_ce(xx, (int)labf.x) + skin_ce(xy, (int)labf.y);

    float dslx = 0.0f, dsly = 0.0f, dsrx = 0.0f, dsry = 0.0f;
#pragma unroll 2
    for (int j = 0; j < BN; ++j) {
        const int cl = (4 + 3 * j) * C2, cr = (52 + 3 * j) * C2;
        const float2 o0 = ob[cl], o1 = ob[cl + C2], o2 = ob[cl + 2 * C2];
        const float2 t0 = tb[cl], t1 = tb[cl + C2], t2 = tb[cl + 2 * C2];
        const float2 p0 = ob[cr], p1 = ob[cr + C2], p2 = ob[cr + 2 * C2];
        const float2 q0 = tb[cr], q1 = tb[cr + C2], q2 = tb[cr + 2 * C2];
        dslx += sq(fsig(o0.x) - fsig(t0.x)) + sq(fsig(o1.x) - fsig(t1.x))
              + sq(fsig(o2.x) - fsig(t2.x));
        dsly += sq(fsig(o0.y) - fsig(t0.y)) + sq(fsig(o1.y) - fsig(t1.y))
              + sq(fsig(o2.y) - fsig(t2.y));
        dsrx += sq(fsig(p0.x) - fsig(q0.x)) + sq(fsig(p1.x) - fsig(q1.x))
              + sq(fsig(p2.x) - fsig(q2.x));
        dsry += sq(fsig(p0.y) - fsig(q0.y)) + sq(fsig(p1.y) - fsig(q1.y))
              + sq(fsig(p2.y) - fsig(q2.y));
    }
    const float dnlx = sqrtf(dslx), dnly = sqrtf(dsly);
    const float dnrx = sqrtf(dsrx), dnry = sqrtf(dsry);

    float v[11];
    v[0]  = bce;
    v[1]  = skin;
    v[2]  = (sx ? dnx : 0.0f) + (sy ? dny : 0.0f);
    v[3]  = ((sx && dnx != 0.0f) ? 1.0f : 0.0f) + ((sy && dny != 0.0f) ? 1.0f : 0.0f);
    v[4]  = dnx + dny;
    v[5]  = (sx ? dnlx : 0.0f) + (sy ? dnly : 0.0f);
    v[6]  = ((sx && dnlx != 0.0f) ? 1.0f : 0.0f) + ((sy && dnly != 0.0f) ? 1.0f : 0.0f);
    v[7]  = dnlx + dnly;
    v[8]  = (sx ? dnrx : 0.0f) + (sy ? dnry : 0.0f);
    v[9]  = ((sx && dnrx != 0.0f) ? 1.0f : 0.0f) + ((sy && dnry != 0.0f) ? 1.0f : 0.0f);
    v[10] = dnrx + dnry;

#pragma unroll
    for (int off = 32; off; off >>= 1) {
#pragma unroll
        for (int i = 0; i < 11; ++i) v[i] += __shfl_xor(v[i], off, 64);
    }
    __shared__ float red[11][4];
    if (lane == 0) {
#pragma unroll
        for (int i = 0; i < 11; ++i) red[i][wv] = v[i];
    }
    __syncthreads();
    if (threadIdx.x < 11) {
        float s = red[threadIdx.x][0] + red[threadIdx.x][1] +
                  red[threadIdx.x][2] + red[threadIdx.x][3];
        int g = (threadIdx.x < 2) ? threadIdx.x : (2 + b * 9 + (threadIdx.x - 2));
        atomicAdd(&ws[g], s);
    }
}

__global__ __launch_bounds__(256) void mvpm_joint4(const float* __restrict__ outp,
                                                   const float* __restrict__ tarp,
                                                   float* __restrict__ ws) {
    const int bj = blockIdx.y;
    const int b = bj >> 4;
    const int j = bj & 15;
    const int C4 = HW / 4;
    const int idx = blockIdx.x * 256 + threadIdx.x;
    const float4* ob = (const float4*)(outp + (size_t)b * 134 * HW);
    const int lane = threadIdx.x & 63;
    const int wv = threadIdx.x >> 6;

    const float4 m  = ((const float4*)(tarp + (size_t)b * 101 * HW))[3 * C4 + idx];
    const float4 s  = ob[(118 + j) * C4 + idx];
    const float4 l0 = ob[(4 + 3 * j) * C4 + idx];
    const float4 l1 = ob[(5 + 3 * j) * C4 + idx];
    const float4 l2 = ob[(6 + 3 * j) * C4 + idx];
    const float4 r0 = ob[(52 + 3 * j) * C4 + idx];
    const float4 r1 = ob[(53 + 3 * j) * C4 + idx];
    const float4 r2 = ob[(54 + 3 * j) * C4 + idx];

    float wx = fsig(s.x) * m.x, wy = fsig(s.y) * m.y,
          wz = fsig(s.z) * m.z, ww = fsig(s.w) * m.w;
    float v[7];
    v[0] = wx + wy + wz + ww;
    wx *= m.x; wy *= m.y; wz *= m.z; ww *= m.w;
    v[1] = fsig(l0.x) * wx + fsig(l0.y) * wy + fsig(l0.z) * wz + fsig(l0.w) * ww;
    v[2] = fsig(l1.x) * wx + fsig(l1.y) * wy + fsig(l1.z) * wz + fsig(l1.w) * ww;
    v[3] = fsig(l2.x) * wx + fsig(l2.y) * wy + fsig(l2.z) * wz + fsig(l2.w) * ww;
    v[4] = fsig(r0.x) * wx + fsig(r0.y) * wy + fsig(r0.z) * wz + fsig(r0.w) * ww;
    v[5] = fsig(r1.x) * wx + fsig(r1.y) * wy + fsig(r1.z) * wz + fsig(r1.w) * ww;
    v[6] = fsig(r2.x) * wx + fsig(r2.y) * wy + fsig(r2.z) * wz + fsig(r2.w) * ww;

#pragma unroll
    for (int off = 32; off; off >>= 1) {
#pragma unroll
        for (int i = 0; i < 7; ++i) v[i] += __shfl_xor(v[i], off, 64);
    }
    __shared__ float red[7][4];
    if (lane == 0) {
#pragma unroll
        for (int i = 0; i < 7; ++i) red[i][wv] = v[i];
    }
    __syncthreads();
    if (threadIdx.x < 7) {
        float sum = red[threadIdx.x][0] + red[threadIdx.x][1] +
                    red[threadIdx.x][2] + red[threadIdx.x][3];
        atomicAdd(&ws[38 + bj * 7 + threadIdx.x], sum);
    }
}

// ===== finalize ===========================================================
__global__ __launch_bounds__(64) void mvpm_fin(const float* __restrict__ ws,
                                               const float* __restrict__ tp,
                                               float* __restrict__ o) {
    const int t = threadIdx.x;
    const int base = 38 + t * 7;

    float S = ws[base] + 1e-5f;
    float ln = 0.0f, rn = 0.0f;
#pragma unroll
    for (int c = 0; c < 3; ++c) {
        float pl = ws[base + 1 + c] / S;
        float tl = 1.0f / (1.0f + expf(-tp[t * 6 + c]));
        ln += (pl - tl) * (pl - tl);
        float pr = ws[base + 4 + c] / S;
        float tr = 1.0f / (1.0f + expf(-tp[t * 6 + 3 + c]));
        rn += (pr - tr) * (pr - tr);
    }
    ln = sqrtf(ln);
    rn = sqrtf(rn);
    float lsum = wred(ln);
    float rsum = wred(rn);

    if (t == 0) {
        float nocs = 0.0f, locm = 0.0f, rotm = 0.0f;
        for (int bb = 0; bb < 4; ++bb) {
            int ba = 2 + bb * 9;
            nocs += (ws[ba + 1] > 0.5f) ? ws[ba + 0] / ws[ba + 1] : ws[ba + 2] * (1.0f / HW);
            locm += (ws[ba + 4] > 0.5f) ? ws[ba + 3] / ws[ba + 4] : ws[ba + 5] * (1.0f / HW);
            rotm += (ws[ba + 7] > 0.5f) ? ws[ba + 6] / ws[ba + 7] : ws[ba + 8] * (1.0f / HW);
        }
        o[0] = nocs * 0.25f;                  // nocs_loss
        o[1] = -ws[0] / (4.0f * HW);          // mask_loss
        o[2] = lsum * (1.0f / 64.0f);         // loc_loss
        o[3] = locm * 0.25f;                  // loc_map_loss
        o[4] = rsum * (1.0f / 64.0f);         // rot_loss
        o[5] = rotm * 0.25f;                  // rot_map_loss
        o[6] = ws[1] / (4.0f * HW);           // skin_loss
    }
}

extern "C" void kernel_launch(void* const* d_in, const int* in_sizes, int n_in,
                              void* d_out, int out_size, void* d_ws, size_t ws_size,
                              hipStream_t stream) {
    const float* outp = (const float*)d_in[0];   // (4,134,256,256)
    const float* tarp = (const float*)d_in[1];   // (4,101,256,256)
    const float* tpos = (const float*)d_in[2];   // (4,16,6)
    float* o  = (float*)d_out;                   // 7 floats
    float* ws = (float*)d_ws;

    hipMemsetAsync(d_ws, 0, 486 * sizeof(float), stream);

    const size_t need = (size_t)(512 + 2 * PART_FLOATS) * sizeof(float);
    if (ws_size >= need) {
        dim3 g1(16, 4, 16);                      // slabs x b x j = 1024 blocks
        k1_joint<<<g1, 256, 0, stream>>>(outp, tarp, ws);
        dim3 g2(64, 4);                          // 256 blocks
        k2_pix<<<g2, 256, 0, stream>>>(outp, tarp, ws);
    } else {
        dim3 gA(HW / 512, 4);
        mvpm_pix2<<<gA, 256, 0, stream>>>(outp, tarp, ws);
        dim3 gB(HW / 1024, 64);
        mvpm_joint4<<<gB, 256, 0, stream>>>(outp, tarp, ws);
    }
    mvpm_fin<<<1, 64, 0, stream>>>(ws, tpos, o);
}